// Round 1
// baseline (906.502 us; speedup 1.0000x reference)
//
#include <hip/hip_runtime.h>
#include <hip/hip_bf16.h>
#include <stdint.h>

// Batched expert FFN: out = relu(x @ w1 + b1) @ w2 + b2
// E=8, T=2048, D=1024, H=4096, fp32 in/out, bf16 MFMA compute (fp32 accum).

using frag8 = __attribute__((ext_vector_type(8))) short;   // 8 bf16 (4 VGPRs)
using f32x4 = __attribute__((ext_vector_type(4))) float;   // MFMA C/D

constexpr int E = 8, T = 2048, D = 1024, H = 4096;
constexpr int BM = 128, BN = 128, BK = 32;
constexpr int LDK = BK + 16;  // 48 bf16 = 96 B row stride: 16B-aligned b128 reads

__device__ __forceinline__ ushort f2bf(float f) {
    union { float f; uint32_t u; } v; v.f = f;
    return (ushort)((v.u + 0x7FFFu + ((v.u >> 16) & 1u)) >> 16);  // RTNE
}

// GEMM1: y1[e][T][H] (bf16) = relu(x[e][T][D] @ w1[e][D][H] + b1[e][H])
__global__ __launch_bounds__(256) void gemm1_kernel(
    const float* __restrict__ x, const float* __restrict__ w1,
    const float* __restrict__ b1, ushort* __restrict__ y1) {
    __shared__ __align__(16) ushort As[BM * LDK];  // As[m][k]
    __shared__ __align__(16) ushort Bs[BN * LDK];  // Bs[n][k] (transposed in staging)

    const int e = blockIdx.z;
    const int m0 = blockIdx.y * BM;
    const int n0 = blockIdx.x * BN;
    const float* xa = x + (size_t)e * T * D + (size_t)m0 * D;
    const float* wb = w1 + (size_t)e * D * H;

    const int tid = threadIdx.x;
    const int lane = tid & 63;
    const int wave = tid >> 6;
    const int waveM = (wave >> 1) * 64;
    const int waveN = (wave & 1) * 64;
    const int col = lane & 15;
    const int quad = lane >> 4;

    // A staging: thread -> row=tid>>3 (+32/pass), float4 at k=(tid&7)*4
    const int ar = tid >> 3;
    const int ak = (tid & 7) * 4;
    // B staging (transpose): thread owns column n=tid&127, k-range (tid>>7)*16..+16
    const int bn = tid & 127;
    const int bk = (tid >> 7) * 16;

    f32x4 acc[4][4] = {};

    for (int k0 = 0; k0 < D; k0 += BK) {
        // stage A: 128x32 fp32 -> bf16
#pragma unroll
        for (int p = 0; p < 4; ++p) {
            const float4 v = *(const float4*)(xa + (size_t)(ar + 32 * p) * D + k0 + ak);
            ushort* dst = &As[(ar + 32 * p) * LDK + ak];
            dst[0] = f2bf(v.x); dst[1] = f2bf(v.y); dst[2] = f2bf(v.z); dst[3] = f2bf(v.w);
        }
        // stage B transposed: Bs[n][k] <- w1[k][n]; reads coalesced along n
        {
            ushort tmp[16];
#pragma unroll
            for (int j = 0; j < 16; ++j)
                tmp[j] = f2bf(wb[(size_t)(k0 + bk + j) * H + n0 + bn]);
            ushort* dst = &Bs[bn * LDK + bk];
#pragma unroll
            for (int j = 0; j < 16; ++j) dst[j] = tmp[j];
        }
        __syncthreads();

        frag8 af[4], bf[4];
#pragma unroll
        for (int i = 0; i < 4; ++i) {
            af[i] = *(const frag8*)&As[(waveM + i * 16 + col) * LDK + quad * 8];
            bf[i] = *(const frag8*)&Bs[(waveN + i * 16 + col) * LDK + quad * 8];
        }
#pragma unroll
        for (int i = 0; i < 4; ++i)
#pragma unroll
            for (int j = 0; j < 4; ++j)
                acc[i][j] = __builtin_amdgcn_mfma_f32_16x16x32_bf16(af[i], bf[j], acc[i][j], 0, 0, 0);
        __syncthreads();
    }

    // epilogue: + bias, relu, bf16 store to y1
    const float* be = b1 + (size_t)e * H;
    ushort* ye = y1 + (size_t)e * T * H;
#pragma unroll
    for (int j = 0; j < 4; ++j) {
        const int n = n0 + waveN + j * 16 + col;
        const float bias = be[n];
#pragma unroll
        for (int i = 0; i < 4; ++i) {
            const int mb = m0 + waveM + i * 16 + quad * 4;
#pragma unroll
            for (int r = 0; r < 4; ++r) {
                float v = acc[i][j][r] + bias;
                v = v > 0.f ? v : 0.f;
                ye[(size_t)(mb + r) * H + n] = f2bf(v);
            }
        }
    }
}

// GEMM2: out[e][T][D] (fp32) = y1[e][T][H] @ w2[e][H][D] + b2[e][D]
__global__ __launch_bounds__(256) void gemm2_kernel(
    const ushort* __restrict__ y1, const float* __restrict__ w2,
    const float* __restrict__ b2, float* __restrict__ out) {
    __shared__ __align__(16) ushort As[BM * LDK];
    __shared__ __align__(16) ushort Bs[BN * LDK];

    const int e = blockIdx.z;
    const int m0 = blockIdx.y * BM;
    const int n0 = blockIdx.x * BN;
    const ushort* ya = y1 + (size_t)e * T * H + (size_t)m0 * H;
    const float* wb = w2 + (size_t)e * H * D;

    const int tid = threadIdx.x;
    const int lane = tid & 63;
    const int wave = tid >> 6;
    const int waveM = (wave >> 1) * 64;
    const int waveN = (wave & 1) * 64;
    const int col = lane & 15;
    const int quad = lane >> 4;

    // A staging (already bf16): row=tid>>2 (+64/pass), 8 bf16 at k=(tid&3)*8
    const int ar = tid >> 2;
    const int ak = (tid & 3) * 8;
    // B staging (transpose + convert)
    const int bn = tid & 127;
    const int bk = (tid >> 7) * 16;

    f32x4 acc[4][4] = {};

    for (int k0 = 0; k0 < H; k0 += BK) {
#pragma unroll
        for (int p = 0; p < 2; ++p) {
            *(frag8*)&As[(ar + 64 * p) * LDK + ak] =
                *(const frag8*)(ya + (size_t)(ar + 64 * p) * H + k0 + ak);
        }
        {
            ushort tmp[16];
#pragma unroll
            for (int j = 0; j < 16; ++j)
                tmp[j] = f2bf(wb[(size_t)(k0 + bk + j) * D + n0 + bn]);
            ushort* dst = &Bs[bn * LDK + bk];
#pragma unroll
            for (int j = 0; j < 16; ++j) dst[j] = tmp[j];
        }
        __syncthreads();

        frag8 af[4], bf[4];
#pragma unroll
        for (int i = 0; i < 4; ++i) {
            af[i] = *(const frag8*)&As[(waveM + i * 16 + col) * LDK + quad * 8];
            bf[i] = *(const frag8*)&Bs[(waveN + i * 16 + col) * LDK + quad * 8];
        }
#pragma unroll
        for (int i = 0; i < 4; ++i)
#pragma unroll
            for (int j = 0; j < 4; ++j)
                acc[i][j] = __builtin_amdgcn_mfma_f32_16x16x32_bf16(af[i], bf[j], acc[i][j], 0, 0, 0);
        __syncthreads();
    }

    const float* be = b2 + (size_t)e * D;
    float* oe = out + (size_t)e * T * D;
#pragma unroll
    for (int j = 0; j < 4; ++j) {
        const int n = n0 + waveN + j * 16 + col;
        const float bias = be[n];
#pragma unroll
        for (int i = 0; i < 4; ++i) {
            const int mb = m0 + waveM + i * 16 + quad * 4;
#pragma unroll
            for (int r = 0; r < 4; ++r)
                oe[(size_t)(mb + r) * D + n] = acc[i][j][r] + bias;
        }
    }
}

extern "C" void kernel_launch(void* const* d_in, const int* in_sizes, int n_in,
                              void* d_out, int out_size, void* d_ws, size_t ws_size,
                              hipStream_t stream) {
    const float* x  = (const float*)d_in[0];   // [E,T,D]
    const float* w1 = (const float*)d_in[1];   // [E,D,H]
    const float* b1 = (const float*)d_in[2];   // [E,1,H]
    const float* w2 = (const float*)d_in[3];   // [E,H,D]
    const float* b2 = (const float*)d_in[4];   // [E,1,D]
    float* out = (float*)d_out;                // [E,T,D]
    ushort* y1 = (ushort*)d_ws;                // [E,T,H] bf16 intermediate: 128 MB

    dim3 g1(H / BN, T / BM, E);  // (32,16,8)
    dim3 g2(D / BN, T / BM, E);  // (8,16,8)
    gemm1_kernel<<<g1, 256, 0, stream>>>(x, w1, b1, y1);
    gemm2_kernel<<<g2, 256, 0, stream>>>(y1, w2, b2, out);
}

// Round 2
// 795.888 us; speedup vs baseline: 1.1390x; 1.1390x over previous
//
#include <hip/hip_runtime.h>
#include <hip/hip_bf16.h>
#include <stdint.h>

// Batched expert FFN: out = relu(x @ w1 + b1) @ w2 + b2
// E=8, T=2048, D=1024, H=4096, fp32 in/out, bf16 MFMA compute (fp32 accum).
//
// Round 2: m97-style GEMMs. Pre-pass casts x to bf16 and transposes w1/w2 to
// [n][k] bf16 in ws (wt region reused for w1t then w2t — graph serializes).
// Both GEMM operands then stage via global_load_lds dwordx4 (16B), removing
// the per-k-step fp32->bf16 VALU convert and the 16-way-conflict scalar LDS
// writes that held round 1 at MfmaUtil 15%.

using frag8 = __attribute__((ext_vector_type(8))) short;   // 8 bf16 (4 VGPRs)
using f32x4 = __attribute__((ext_vector_type(4))) float;   // MFMA C/D

constexpr int E = 8, T = 2048, D = 1024, H = 4096;
constexpr int BM = 128, BN = 128, BK = 32;

__device__ __forceinline__ ushort f2bf(float f) {
    union { float f; uint32_t u; } v; v.f = f;
    return (ushort)((v.u + 0x7FFFu + ((v.u >> 16) & 1u)) >> 16);  // RTNE
}

__device__ __forceinline__ void load16_to_lds(const void* g, void* l) {
    __builtin_amdgcn_global_load_lds(
        (const __attribute__((address_space(1))) uint32_t*)g,
        (__attribute__((address_space(3))) uint32_t*)l, 16, 0, 0);
}

// ---------- prep kernels ----------

// fp32 -> bf16, 4 elems/thread, n divisible by 1024
__global__ __launch_bounds__(256) void cvt_bf16_kernel(
    const float* __restrict__ in, ushort* __restrict__ out) {
    const size_t i = ((size_t)blockIdx.x * 256 + threadIdx.x) * 4;
    const float4 v = *(const float4*)(in + i);
    ushort4 o;
    o.x = f2bf(v.x); o.y = f2bf(v.y); o.z = f2bf(v.z); o.w = f2bf(v.w);
    *(ushort4*)(out + i) = o;
}

// in[e][K][N] fp32 -> out[e][N][K] bf16 (transpose + cast), 32x32 tiles
__global__ __launch_bounds__(256) void transpose_cvt_kernel(
    const float* __restrict__ in, ushort* __restrict__ out, int K, int N) {
    __shared__ ushort tile[32][33];
    const int e = blockIdx.z;
    const int k0 = blockIdx.y * 32, n0 = blockIdx.x * 32;
    const float* ie = in + (size_t)e * K * N;
    ushort* oe = out + (size_t)e * N * K;
    const int tx = threadIdx.x & 31, ty = threadIdx.x >> 5;  // ty 0..7
#pragma unroll
    for (int p = 0; p < 4; ++p) {
        const int k = ty + p * 8;
        tile[k][tx] = f2bf(ie[(size_t)(k0 + k) * N + n0 + tx]);
    }
    __syncthreads();
#pragma unroll
    for (int p = 0; p < 4; ++p) {
        const int n = ty + p * 8;
        oe[(size_t)(n0 + n) * K + k0 + tx] = tile[tx][n];
    }
}

// ---------- m97-style GEMM ----------
// A: bf16 [E][T][K] row-major; B: bf16 [E][N][K] (n-major, k-contiguous);
// bias fp32 [E][N].  RELU_BF16: out bf16 [E][T][N] with relu; else fp32 + bias.
template <bool RELU_BF16>
__global__ __launch_bounds__(256) void mfma_gemm_kernel(
    const ushort* __restrict__ A, const ushort* __restrict__ B,
    const float* __restrict__ bias, void* __restrict__ Cout,
    const int K, const int N) {
    // unpadded m97 layout: row = 32 bf16 = 64 B
    __shared__ __align__(16) ushort As[BM * BK];  // 8 KB
    __shared__ __align__(16) ushort Bs[BN * BK];  // 8 KB

    const int e = blockIdx.z;
    const int m0 = blockIdx.y * BM;
    const int n0 = blockIdx.x * BN;
    const ushort* Ae = A + (size_t)e * T * K + (size_t)m0 * K;
    const ushort* Be = B + (size_t)e * N * K + (size_t)n0 * K;

    const int tid = threadIdx.x;
    const int lane = tid & 63;
    const int wave = tid >> 6;
    const int waveM = (wave >> 1) * 64;
    const int waveN = (wave & 1) * 64;
    const int col = lane & 15;
    const int quad = lane >> 4;

    // staging: tile = 512 x 16B chunks; chunk c -> row c>>2, k-chunk c&3.
    // thread t owns chunks t and t+256. LDS dest = chunk*16 B: per-wave
    // uniform base + lane*16 (global_load_lds requirement).
    const int c1 = tid, c2 = tid + 256;
    const ushort* gA1 = Ae + (size_t)(c1 >> 2) * K + (c1 & 3) * 8;
    const ushort* gA2 = Ae + (size_t)(c2 >> 2) * K + (c2 & 3) * 8;
    const ushort* gB1 = Be + (size_t)(c1 >> 2) * K + (c1 & 3) * 8;
    const ushort* gB2 = Be + (size_t)(c2 >> 2) * K + (c2 & 3) * 8;
    ushort* lA1 = As + wave * 512;          // (wave*64 chunks)*8 ushorts
    ushort* lA2 = As + 2048 + wave * 512;
    ushort* lB1 = Bs + wave * 512;
    ushort* lB2 = Bs + 2048 + wave * 512;

    f32x4 acc[4][4] = {};

    for (int k0 = 0; k0 < K; k0 += BK) {
        load16_to_lds(gA1 + k0, lA1);
        load16_to_lds(gA2 + k0, lA2);
        load16_to_lds(gB1 + k0, lB1);
        load16_to_lds(gB2 + k0, lB2);
        __syncthreads();  // drains vmcnt(0) then barrier

        frag8 af[4], bf[4];
#pragma unroll
        for (int i = 0; i < 4; ++i) {
            af[i] = *(const frag8*)&As[(waveM + i * 16 + col) * BK + quad * 8];
            bf[i] = *(const frag8*)&Bs[(waveN + i * 16 + col) * BK + quad * 8];
        }
#pragma unroll
        for (int i = 0; i < 4; ++i)
#pragma unroll
            for (int j = 0; j < 4; ++j)
                acc[i][j] = __builtin_amdgcn_mfma_f32_16x16x32_bf16(af[i], bf[j], acc[i][j], 0, 0, 0);
        __syncthreads();
    }

    const float* be = bias + (size_t)e * N;
#pragma unroll
    for (int j = 0; j < 4; ++j) {
        const int n = n0 + waveN + j * 16 + col;
        const float bv = be[n];
#pragma unroll
        for (int i = 0; i < 4; ++i) {
            const int mb = m0 + waveM + i * 16 + quad * 4;
#pragma unroll
            for (int r = 0; r < 4; ++r) {
                float v = acc[i][j][r] + bv;
                if (RELU_BF16) {
                    v = v > 0.f ? v : 0.f;
                    ((ushort*)Cout)[(size_t)e * T * N + (size_t)(mb + r) * N + n] = f2bf(v);
                } else {
                    ((float*)Cout)[(size_t)e * T * N + (size_t)(mb + r) * N + n] = v;
                }
            }
        }
    }
}

// ---------- round-1 fallback (ws too small for prep regions) ----------

constexpr int LDK = BK + 16;

__global__ __launch_bounds__(256) void fb_gemm1_kernel(
    const float* __restrict__ x, const float* __restrict__ w1,
    const float* __restrict__ b1, ushort* __restrict__ y1) {
    __shared__ __align__(16) ushort As[BM * LDK];
    __shared__ __align__(16) ushort Bs[BN * LDK];
    const int e = blockIdx.z, m0 = blockIdx.y * BM, n0 = blockIdx.x * BN;
    const float* xa = x + (size_t)e * T * D + (size_t)m0 * D;
    const float* wb = w1 + (size_t)e * D * H;
    const int tid = threadIdx.x, lane = tid & 63, wave = tid >> 6;
    const int waveM = (wave >> 1) * 64, waveN = (wave & 1) * 64;
    const int col = lane & 15, quad = lane >> 4;
    const int ar = tid >> 3, ak = (tid & 7) * 4;
    const int bn = tid & 127, bk = (tid >> 7) * 16;
    f32x4 acc[4][4] = {};
    for (int k0 = 0; k0 < D; k0 += BK) {
#pragma unroll
        for (int p = 0; p < 4; ++p) {
            const float4 v = *(const float4*)(xa + (size_t)(ar + 32 * p) * D + k0 + ak);
            ushort* dst = &As[(ar + 32 * p) * LDK + ak];
            dst[0] = f2bf(v.x); dst[1] = f2bf(v.y); dst[2] = f2bf(v.z); dst[3] = f2bf(v.w);
        }
        {
            ushort tmp[16];
#pragma unroll
            for (int j = 0; j < 16; ++j)
                tmp[j] = f2bf(wb[(size_t)(k0 + bk + j) * H + n0 + bn]);
            ushort* dst = &Bs[bn * LDK + bk];
#pragma unroll
            for (int j = 0; j < 16; ++j) dst[j] = tmp[j];
        }
        __syncthreads();
        frag8 af[4], bf[4];
#pragma unroll
        for (int i = 0; i < 4; ++i) {
            af[i] = *(const frag8*)&As[(waveM + i * 16 + col) * LDK + quad * 8];
            bf[i] = *(const frag8*)&Bs[(waveN + i * 16 + col) * LDK + quad * 8];
        }
#pragma unroll
        for (int i = 0; i < 4; ++i)
#pragma unroll
            for (int j = 0; j < 4; ++j)
                acc[i][j] = __builtin_amdgcn_mfma_f32_16x16x32_bf16(af[i], bf[j], acc[i][j], 0, 0, 0);
        __syncthreads();
    }
    const float* be = b1 + (size_t)e * H;
    ushort* ye = y1 + (size_t)e * T * H;
#pragma unroll
    for (int j = 0; j < 4; ++j) {
        const int n = n0 + waveN + j * 16 + col;
        const float bias = be[n];
#pragma unroll
        for (int i = 0; i < 4; ++i) {
            const int mb = m0 + waveM + i * 16 + quad * 4;
#pragma unroll
            for (int r = 0; r < 4; ++r) {
                float v = acc[i][j][r] + bias;
                v = v > 0.f ? v : 0.f;
                ye[(size_t)(mb + r) * H + n] = f2bf(v);
            }
        }
    }
}

__global__ __launch_bounds__(256) void fb_gemm2_kernel(
    const ushort* __restrict__ y1, const float* __restrict__ w2,
    const float* __restrict__ b2, float* __restrict__ out) {
    __shared__ __align__(16) ushort As[BM * LDK];
    __shared__ __align__(16) ushort Bs[BN * LDK];
    const int e = blockIdx.z, m0 = blockIdx.y * BM, n0 = blockIdx.x * BN;
    const ushort* ya = y1 + (size_t)e * T * H + (size_t)m0 * H;
    const float* wb = w2 + (size_t)e * H * D;
    const int tid = threadIdx.x, lane = tid & 63, wave = tid >> 6;
    const int waveM = (wave >> 1) * 64, waveN = (wave & 1) * 64;
    const int col = lane & 15, quad = lane >> 4;
    const int ar = tid >> 2, ak = (tid & 3) * 8;
    const int bn = tid & 127, bk = (tid >> 7) * 16;
    f32x4 acc[4][4] = {};
    for (int k0 = 0; k0 < H; k0 += BK) {
#pragma unroll
        for (int p = 0; p < 2; ++p)
            *(frag8*)&As[(ar + 64 * p) * LDK + ak] =
                *(const frag8*)(ya + (size_t)(ar + 64 * p) * H + k0 + ak);
        {
            ushort tmp[16];
#pragma unroll
            for (int j = 0; j < 16; ++j)
                tmp[j] = f2bf(wb[(size_t)(k0 + bk + j) * D + n0 + bn]);
            ushort* dst = &Bs[bn * LDK + bk];
#pragma unroll
            for (int j = 0; j < 16; ++j) dst[j] = tmp[j];
        }
        __syncthreads();
        frag8 af[4], bf[4];
#pragma unroll
        for (int i = 0; i < 4; ++i) {
            af[i] = *(const frag8*)&As[(waveM + i * 16 + col) * LDK + quad * 8];
            bf[i] = *(const frag8*)&Bs[(waveN + i * 16 + col) * LDK + quad * 8];
        }
#pragma unroll
        for (int i = 0; i < 4; ++i)
#pragma unroll
            for (int j = 0; j < 4; ++j)
                acc[i][j] = __builtin_amdgcn_mfma_f32_16x16x32_bf16(af[i], bf[j], acc[i][j], 0, 0, 0);
        __syncthreads();
    }
    const float* be = b2 + (size_t)e * D;
    float* oe = out + (size_t)e * T * D;
#pragma unroll
    for (int j = 0; j < 4; ++j) {
        const int n = n0 + waveN + j * 16 + col;
        const float bias = be[n];
#pragma unroll
        for (int i = 0; i < 4; ++i) {
            const int mb = m0 + waveM + i * 16 + quad * 4;
#pragma unroll
            for (int r = 0; r < 4; ++r)
                oe[(size_t)(mb + r) * D + n] = acc[i][j][r] + bias;
        }
    }
}

extern "C" void kernel_launch(void* const* d_in, const int* in_sizes, int n_in,
                              void* d_out, int out_size, void* d_ws, size_t ws_size,
                              hipStream_t stream) {
    const float* x  = (const float*)d_in[0];   // [E,T,D]
    const float* w1 = (const float*)d_in[1];   // [E,D,H]
    const float* b1 = (const float*)d_in[2];   // [E,1,H]
    const float* w2 = (const float*)d_in[3];   // [E,H,D]
    const float* b2 = (const float*)d_in[4];   // [E,1,D]
    float* out = (float*)d_out;                // [E,T,D]

    const size_t y1_bytes = (size_t)E * T * H * 2;  // 128 MB
    const size_t wt_bytes = (size_t)E * D * H * 2;  //  64 MB (shared w1t/w2t)
    const size_t xb_bytes = (size_t)E * T * D * 2;  //  32 MB
    const size_t need = y1_bytes + wt_bytes + xb_bytes;  // 224 MB

    if (ws_size >= need) {
        ushort* y1 = (ushort*)d_ws;
        ushort* wt = (ushort*)((char*)d_ws + y1_bytes);
        ushort* xb = (ushort*)((char*)d_ws + y1_bytes + wt_bytes);

        // 1. x -> bf16
        cvt_bf16_kernel<<<(E * T * D) / (256 * 4), 256, 0, stream>>>(x, xb);
        // 2. w1 [E][D][H] -> wt [E][H][D] bf16
        transpose_cvt_kernel<<<dim3(H / 32, D / 32, E), 256, 0, stream>>>(w1, wt, D, H);
        // 3. gemm1: y1 = relu(xb @ w1 + b1), bf16
        mfma_gemm_kernel<true><<<dim3(H / BN, T / BM, E), 256, 0, stream>>>(xb, wt, b1, y1, D, H);
        // 4. w2 [E][H][D] -> wt [E][D][H] bf16 (region reuse)
        transpose_cvt_kernel<<<dim3(D / 32, H / 32, E), 256, 0, stream>>>(w2, wt, H, D);
        // 5. gemm2: out = y1 @ w2 + b2, fp32
        mfma_gemm_kernel<false><<<dim3(D / BN, T / BM, E), 256, 0, stream>>>(y1, wt, b2, out, H, D);
    } else {
        ushort* y1 = (ushort*)d_ws;  // 128 MB
        fb_gemm1_kernel<<<dim3(H / BN, T / BM, E), 256, 0, stream>>>(x, w1, b1, y1);
        fb_gemm2_kernel<<<dim3(D / BN, T / BM, E), 256, 0, stream>>>(y1, w2, b2, out);
    }
}

// Round 3
// 771.174 us; speedup vs baseline: 1.1755x; 1.0320x over previous
//
#include <hip/hip_runtime.h>
#include <hip/hip_bf16.h>
#include <stdint.h>

// Batched expert FFN: out = relu(x @ w1 + b1) @ w2 + b2
// E=8, T=2048, D=1024, H=4096, fp32 in/out, bf16 MFMA compute (fp32 accum).
//
// Round 3: (a) XCD-aware 1D swizzle — expert = bid&7 (8 experts == 8 XCDs),
// M-fastest within expert so each XCD's L2 keeps the B n-slab hot and each
// XCD touches exactly one expert's data (round 2: 670 MB FETCH vs 192 MB
// compulsory). (b) vectorized transpose prep (float4 in, ushort8 out).

using frag8 = __attribute__((ext_vector_type(8))) short;   // 8 bf16 (4 VGPRs)
using f32x4 = __attribute__((ext_vector_type(4))) float;   // MFMA C/D

constexpr int E = 8, T = 2048, D = 1024, H = 4096;
constexpr int BM = 128, BN = 128, BK = 32;

__device__ __forceinline__ ushort f2bf(float f) {
    union { float f; uint32_t u; } v; v.f = f;
    return (ushort)((v.u + 0x7FFFu + ((v.u >> 16) & 1u)) >> 16);  // RTNE
}

__device__ __forceinline__ void load16_to_lds(const void* g, void* l) {
    __builtin_amdgcn_global_load_lds(
        (const __attribute__((address_space(1))) uint32_t*)g,
        (__attribute__((address_space(3))) uint32_t*)l, 16, 0, 0);
}

// ---------- prep kernels ----------

// fp32 -> bf16, 4 elems/thread
__global__ __launch_bounds__(256) void cvt_bf16_kernel(
    const float* __restrict__ in, ushort* __restrict__ out) {
    const size_t i = ((size_t)blockIdx.x * 256 + threadIdx.x) * 4;
    const float4 v = *(const float4*)(in + i);
    ushort4 o;
    o.x = f2bf(v.x); o.y = f2bf(v.y); o.z = f2bf(v.z); o.w = f2bf(v.w);
    *(ushort4*)(out + i) = o;
}

// in[e][K][N] fp32 -> out[e][N][K] bf16; 64x64 tiles, vectorized both sides
__global__ __launch_bounds__(256) void transpose_cvt_kernel(
    const float* __restrict__ in, ushort* __restrict__ out, int K, int N) {
    __shared__ __align__(16) ushort tile[64][72];  // +8 pad: 144 B rows, 16B-aligned
    const int e = blockIdx.z;
    const int k0 = blockIdx.y * 64, n0 = blockIdx.x * 64;
    const float* ie = in + (size_t)e * K * N + (size_t)k0 * N + n0;
    ushort* oe = out + (size_t)e * N * K + (size_t)n0 * K + k0;
    const int t = threadIdx.x;
    // load: row k = t>>2, 16 floats (4 float4) at n = (t&3)*16
    const int lk = t >> 2;
    const int ln = (t & 3) * 16;
#pragma unroll
    for (int v = 0; v < 4; ++v) {
        const float4 f = *(const float4*)(ie + (size_t)lk * N + ln + v * 4);
        tile[ln + v * 4 + 0][lk] = f2bf(f.x);
        tile[ln + v * 4 + 1][lk] = f2bf(f.y);
        tile[ln + v * 4 + 2][lk] = f2bf(f.z);
        tile[ln + v * 4 + 3][lk] = f2bf(f.w);
    }
    __syncthreads();
    // store: row n = t>>2, 16 k (2x ushort8=16B) at k = (t&3)*16
    const int on = t >> 2;
    const int ok = (t & 3) * 16;
#pragma unroll
    for (int v = 0; v < 2; ++v)
        *(frag8*)(oe + (size_t)on * K + ok + v * 8) = *(const frag8*)&tile[on][ok + v * 8];
}

// ---------- m97-style GEMM with XCD swizzle ----------
// A: bf16 [E][T][K] row-major; B: bf16 [E][N][K]; bias fp32 [E][N].
// 1D grid = E * (T/BM) * (N/BN); bid&7 = expert (XCD), M-fastest within.
template <bool RELU_BF16>
__global__ __launch_bounds__(256) void mfma_gemm_kernel(
    const ushort* __restrict__ A, const ushort* __restrict__ B,
    const float* __restrict__ bias, void* __restrict__ Cout,
    const int K, const int N) {
    __shared__ __align__(16) ushort As[BM * BK];  // 8 KB, unpadded m97 layout
    __shared__ __align__(16) ushort Bs[BN * BK];  // 8 KB

    const int bid = blockIdx.x;
    const int e = bid & 7;          // expert == XCD (round-robin heuristic)
    const int s = bid >> 3;
    const int m0 = (s & 15) * BM;   // M-fastest: B n-slab stays L2-hot
    const int n0 = (s >> 4) * BN;

    const ushort* Ae = A + (size_t)e * T * K + (size_t)m0 * K;
    const ushort* Be = B + (size_t)e * N * K + (size_t)n0 * K;

    const int tid = threadIdx.x;
    const int lane = tid & 63;
    const int wave = tid >> 6;
    const int waveM = (wave >> 1) * 64;
    const int waveN = (wave & 1) * 64;
    const int col = lane & 15;
    const int quad = lane >> 4;

    // staging: tile = 512 x 16B chunks; chunk c -> row c>>2, k-chunk c&3.
    const int c1 = tid, c2 = tid + 256;
    const ushort* gA1 = Ae + (size_t)(c1 >> 2) * K + (c1 & 3) * 8;
    const ushort* gA2 = Ae + (size_t)(c2 >> 2) * K + (c2 & 3) * 8;
    const ushort* gB1 = Be + (size_t)(c1 >> 2) * K + (c1 & 3) * 8;
    const ushort* gB2 = Be + (size_t)(c2 >> 2) * K + (c2 & 3) * 8;
    ushort* lA1 = As + wave * 512;
    ushort* lA2 = As + 2048 + wave * 512;
    ushort* lB1 = Bs + wave * 512;
    ushort* lB2 = Bs + 2048 + wave * 512;

    f32x4 acc[4][4] = {};

    for (int k0 = 0; k0 < K; k0 += BK) {
        load16_to_lds(gA1 + k0, lA1);
        load16_to_lds(gA2 + k0, lA2);
        load16_to_lds(gB1 + k0, lB1);
        load16_to_lds(gB2 + k0, lB2);
        __syncthreads();

        frag8 af[4], bf[4];
#pragma unroll
        for (int i = 0; i < 4; ++i) {
            af[i] = *(const frag8*)&As[(waveM + i * 16 + col) * BK + quad * 8];
            bf[i] = *(const frag8*)&Bs[(waveN + i * 16 + col) * BK + quad * 8];
        }
#pragma unroll
        for (int i = 0; i < 4; ++i)
#pragma unroll
            for (int j = 0; j < 4; ++j)
                acc[i][j] = __builtin_amdgcn_mfma_f32_16x16x32_bf16(af[i], bf[j], acc[i][j], 0, 0, 0);
        __syncthreads();
    }

    const float* be = bias + (size_t)e * N;
#pragma unroll
    for (int j = 0; j < 4; ++j) {
        const int n = n0 + waveN + j * 16 + col;
        const float bv = be[n];
#pragma unroll
        for (int i = 0; i < 4; ++i) {
            const int mb = m0 + waveM + i * 16 + quad * 4;
#pragma unroll
            for (int r = 0; r < 4; ++r) {
                float v = acc[i][j][r] + bv;
                if (RELU_BF16) {
                    v = v > 0.f ? v : 0.f;
                    ((ushort*)Cout)[(size_t)e * T * N + (size_t)(mb + r) * N + n] = f2bf(v);
                } else {
                    ((float*)Cout)[(size_t)e * T * N + (size_t)(mb + r) * N + n] = v;
                }
            }
        }
    }
}

// ---------- round-1 fallback (ws too small for prep regions) ----------

constexpr int LDK = BK + 16;

__global__ __launch_bounds__(256) void fb_gemm1_kernel(
    const float* __restrict__ x, const float* __restrict__ w1,
    const float* __restrict__ b1, ushort* __restrict__ y1) {
    __shared__ __align__(16) ushort As[BM * LDK];
    __shared__ __align__(16) ushort Bs[BN * LDK];
    const int e = blockIdx.z, m0 = blockIdx.y * BM, n0 = blockIdx.x * BN;
    const float* xa = x + (size_t)e * T * D + (size_t)m0 * D;
    const float* wb = w1 + (size_t)e * D * H;
    const int tid = threadIdx.x, lane = tid & 63, wave = tid >> 6;
    const int waveM = (wave >> 1) * 64, waveN = (wave & 1) * 64;
    const int col = lane & 15, quad = lane >> 4;
    const int ar = tid >> 3, ak = (tid & 7) * 4;
    const int bn = tid & 127, bk = (tid >> 7) * 16;
    f32x4 acc[4][4] = {};
    for (int k0 = 0; k0 < D; k0 += BK) {
#pragma unroll
        for (int p = 0; p < 4; ++p) {
            const float4 v = *(const float4*)(xa + (size_t)(ar + 32 * p) * D + k0 + ak);
            ushort* dst = &As[(ar + 32 * p) * LDK + ak];
            dst[0] = f2bf(v.x); dst[1] = f2bf(v.y); dst[2] = f2bf(v.z); dst[3] = f2bf(v.w);
        }
        {
            ushort tmp[16];
#pragma unroll
            for (int j = 0; j < 16; ++j)
                tmp[j] = f2bf(wb[(size_t)(k0 + bk + j) * H + n0 + bn]);
            ushort* dst = &Bs[bn * LDK + bk];
#pragma unroll
            for (int j = 0; j < 16; ++j) dst[j] = tmp[j];
        }
        __syncthreads();
        frag8 af[4], bf[4];
#pragma unroll
        for (int i = 0; i < 4; ++i) {
            af[i] = *(const frag8*)&As[(waveM + i * 16 + col) * LDK + quad * 8];
            bf[i] = *(const frag8*)&Bs[(waveN + i * 16 + col) * LDK + quad * 8];
        }
#pragma unroll
        for (int i = 0; i < 4; ++i)
#pragma unroll
            for (int j = 0; j < 4; ++j)
                acc[i][j] = __builtin_amdgcn_mfma_f32_16x16x32_bf16(af[i], bf[j], acc[i][j], 0, 0, 0);
        __syncthreads();
    }
    const float* be = b1 + (size_t)e * H;
    ushort* ye = y1 + (size_t)e * T * H;
#pragma unroll
    for (int j = 0; j < 4; ++j) {
        const int n = n0 + waveN + j * 16 + col;
        const float bias = be[n];
#pragma unroll
        for (int i = 0; i < 4; ++i) {
            const int mb = m0 + waveM + i * 16 + quad * 4;
#pragma unroll
            for (int r = 0; r < 4; ++r) {
                float v = acc[i][j][r] + bias;
                v = v > 0.f ? v : 0.f;
                ye[(size_t)(mb + r) * H + n] = f2bf(v);
            }
        }
    }
}

__global__ __launch_bounds__(256) void fb_gemm2_kernel(
    const ushort* __restrict__ y1, const float* __restrict__ w2,
    const float* __restrict__ b2, float* __restrict__ out) {
    __shared__ __align__(16) ushort As[BM * LDK];
    __shared__ __align__(16) ushort Bs[BN * LDK];
    const int e = blockIdx.z, m0 = blockIdx.y * BM, n0 = blockIdx.x * BN;
    const ushort* ya = y1 + (size_t)e * T * H + (size_t)m0 * H;
    const float* wb = w2 + (size_t)e * H * D;
    const int tid = threadIdx.x, lane = tid & 63, wave = tid >> 6;
    const int waveM = (wave >> 1) * 64, waveN = (wave & 1) * 64;
    const int col = lane & 15, quad = lane >> 4;
    const int ar = tid >> 2, ak = (tid & 3) * 8;
    const int bn = tid & 127, bk = (tid >> 7) * 16;
    f32x4 acc[4][4] = {};
    for (int k0 = 0; k0 < H; k0 += BK) {
#pragma unroll
        for (int p = 0; p < 2; ++p)
            *(frag8*)&As[(ar + 64 * p) * LDK + ak] =
                *(const frag8*)(ya + (size_t)(ar + 64 * p) * H + k0 + ak);
        {
            ushort tmp[16];
#pragma unroll
            for (int j = 0; j < 16; ++j)
                tmp[j] = f2bf(wb[(size_t)(k0 + bk + j) * D + n0 + bn]);
            ushort* dst = &Bs[bn * LDK + bk];
#pragma unroll
            for (int j = 0; j < 16; ++j) dst[j] = tmp[j];
        }
        __syncthreads();
        frag8 af[4], bf[4];
#pragma unroll
        for (int i = 0; i < 4; ++i) {
            af[i] = *(const frag8*)&As[(waveM + i * 16 + col) * LDK + quad * 8];
            bf[i] = *(const frag8*)&Bs[(waveN + i * 16 + col) * LDK + quad * 8];
        }
#pragma unroll
        for (int i = 0; i < 4; ++i)
#pragma unroll
            for (int j = 0; j < 4; ++j)
                acc[i][j] = __builtin_amdgcn_mfma_f32_16x16x32_bf16(af[i], bf[j], acc[i][j], 0, 0, 0);
        __syncthreads();
    }
    const float* be = b2 + (size_t)e * D;
    float* oe = out + (size_t)e * T * D;
#pragma unroll
    for (int j = 0; j < 4; ++j) {
        const int n = n0 + waveN + j * 16 + col;
        const float bias = be[n];
#pragma unroll
        for (int i = 0; i < 4; ++i) {
            const int mb = m0 + waveM + i * 16 + quad * 4;
#pragma unroll
            for (int r = 0; r < 4; ++r)
                oe[(size_t)(mb + r) * D + n] = acc[i][j][r] + bias;
        }
    }
}

extern "C" void kernel_launch(void* const* d_in, const int* in_sizes, int n_in,
                              void* d_out, int out_size, void* d_ws, size_t ws_size,
                              hipStream_t stream) {
    const float* x  = (const float*)d_in[0];   // [E,T,D]
    const float* w1 = (const float*)d_in[1];   // [E,D,H]
    const float* b1 = (const float*)d_in[2];   // [E,1,H]
    const float* w2 = (const float*)d_in[3];   // [E,H,D]
    const float* b2 = (const float*)d_in[4];   // [E,1,D]
    float* out = (float*)d_out;                // [E,T,D]

    const size_t y1_bytes = (size_t)E * T * H * 2;  // 128 MB
    const size_t wt_bytes = (size_t)E * D * H * 2;  //  64 MB (shared w1t/w2t)
    const size_t xb_bytes = (size_t)E * T * D * 2;  //  32 MB
    const size_t need = y1_bytes + wt_bytes + xb_bytes;  // 224 MB

    if (ws_size >= need) {
        ushort* y1 = (ushort*)d_ws;
        ushort* wt = (ushort*)((char*)d_ws + y1_bytes);
        ushort* xb = (ushort*)((char*)d_ws + y1_bytes + wt_bytes);

        // 1. x -> bf16
        cvt_bf16_kernel<<<(E * T * D) / (256 * 4), 256, 0, stream>>>(x, xb);
        // 2. w1 [E][D][H] -> wt [E][H][D] bf16
        transpose_cvt_kernel<<<dim3(H / 64, D / 64, E), 256, 0, stream>>>(w1, wt, D, H);
        // 3. gemm1: y1 = relu(xb @ w1 + b1), bf16  (1D swizzled grid)
        mfma_gemm_kernel<true><<<E * (T / BM) * (H / BN), 256, 0, stream>>>(xb, wt, b1, y1, D, H);
        // 4. w2 [E][H][D] -> wt [E][D][H] bf16 (region reuse)
        transpose_cvt_kernel<<<dim3(D / 64, H / 64, E), 256, 0, stream>>>(w2, wt, H, D);
        // 5. gemm2: out = y1 @ w2 + b2, fp32
        mfma_gemm_kernel<false><<<E * (T / BM) * (D / BN), 256, 0, stream>>>(y1, wt, b2, out, H, D);
    } else {
        ushort* y1 = (ushort*)d_ws;
        fb_gemm1_kernel<<<dim3(H / BN, T / BM, E), 256, 0, stream>>>(x, w1, b1, y1);
        fb_gemm2_kernel<<<dim3(D / BN, T / BM, E), 256, 0, stream>>>(y1, w2, b2, out);
    }
}